// Round 1
// baseline (3182.857 us; speedup 1.0000x reference)
//
#include <hip/hip_runtime.h>
#include <cstdint>

#define DEV __device__ __forceinline__

static constexpr float INV_SQRT_W = 0.04419417382415922f; // 1/sqrt(512)
static constexpr float SQRT2_F    = 1.41421356237309515f;

DEV int imax(int a, int b) { return a > b ? a : b; }
DEV int imin(int a, int b) { return a < b ? a : b; }

// styles[n][c] = w[n]·aw[c] / sqrt(512) + ab[c]
__global__ __launch_bounds__(256) void k_styles(const float* __restrict__ w,
    const float* __restrict__ aw, const float* __restrict__ ab,
    float* __restrict__ styles) {
  int t = blockIdx.x * 256 + threadIdx.x;        // 4096
  int n = t >> 9, c = t & 511;
  const float* wr = w + n * 512;
  const float* ar = aw + c * 512;
  float s = 0.f;
  for (int k = 0; k < 512; ++k) s = fmaf(wr[k], ar[k], s);
  styles[t] = s * INV_SQRT_W + ab[c];
}

// wsq[o][i] = sum_k w[o,i,k]^2 ; wscale[o] = rsqrt(mean over 4608)
__global__ __launch_bounds__(256) void k_wstats(const float* __restrict__ cw,
    float* __restrict__ wsq, float* __restrict__ wscale) {
  int o = blockIdx.x;
  __shared__ float red[256];
  float tot = 0.f;
  for (int i = threadIdx.x; i < 512; i += 256) {
    const float* p = cw + (o * 512 + i) * 9;
    float s = 0.f;
#pragma unroll
    for (int k = 0; k < 9; ++k) s = fmaf(p[k], p[k], s);
    wsq[o * 512 + i] = s;
    tot += s;
  }
  red[threadIdx.x] = tot;
  __syncthreads();
  for (int st = 128; st > 0; st >>= 1) {
    if (threadIdx.x < st) red[threadIdx.x] += red[threadIdx.x + st];
    __syncthreads();
  }
  if (threadIdx.x == 0) wscale[o] = rsqrtf(red[0] / 4608.f);
}

// sg = rsqrt(mean(styles^2)) over all 4096
__global__ __launch_bounds__(256) void k_sg(const float* __restrict__ styles,
                                            float* __restrict__ sg) {
  __shared__ float red[256];
  float s = 0.f;
  for (int t = threadIdx.x; t < 4096; t += 256) { float v = styles[t]; s = fmaf(v, v, s); }
  red[threadIdx.x] = s;
  __syncthreads();
  for (int st = 128; st > 0; st >>= 1) {
    if (threadIdx.x < st) red[threadIdx.x] += red[threadIdx.x + st];
    __syncthreads();
  }
  if (threadIdx.x == 0) sg[0] = rsqrtf(red[0] / 4096.f);
}

// coef[n][o] = wscale[o]*sg*ig * rsqrt((wscale[o]*sg)^2 * sum_i s^2[n,i]*wsq[o,i] + 1e-8)
__global__ __launch_bounds__(256) void k_coef(const float* __restrict__ styles,
    const float* __restrict__ wsq, const float* __restrict__ wscale,
    const float* __restrict__ sg, const float* __restrict__ ema,
    float* __restrict__ coef) {
  int n = blockIdx.x >> 1;
  int o = ((blockIdx.x & 1) << 8) + threadIdx.x;
  __shared__ float s2[512];
  for (int i = threadIdx.x; i < 512; i += 256) { float v = styles[n * 512 + i]; s2[i] = v * v; }
  __syncthreads();
  const float* wq = wsq + o * 512;
  float Q = 0.f;
  for (int i = 0; i < 512; ++i) Q = fmaf(s2[i], wq[i], Q);
  float a = wscale[o] * sg[0];
  float ig = rsqrtf(ema[0]);
  coef[n * 512 + o] = a * ig * rsqrtf(a * a * Q + 1e-8f);
}

// wT[(i*9+k9)*512 + o] = cw[(o*512+i)*9 + k9]  (coalesced o-major staging)
__global__ __launch_bounds__(256) void k_wT(const float* __restrict__ cw,
                                            float* __restrict__ wT) {
  int t = blockIdx.x * 256 + threadIdx.x;        // 2359296 exact
  int o = t & 511;
  int rest = t >> 9;
  int k9 = rest % 9;
  int i = rest / 9;
  wT[t] = cw[(o * 512 + i) * 9 + k9];
}

// Direct fp32 conv 3x3, pad 2, out [8,512,66,66], x scaled by styles at stage,
// epilogue scaled by coef. Block: 32 o x 256 flat-spatial; thread: 8 o x 4 sp.
#define ICB 8
__global__ __launch_bounds__(256) void k_conv(const float* __restrict__ x,
    const float* __restrict__ wT, const float* __restrict__ styles,
    const float* __restrict__ coef, float* __restrict__ convout) {
  const int n = blockIdx.z;
  const int oBase = blockIdx.y * 32;
  const int spBase = blockIdx.x * 256;
  const int tid = threadIdx.x;
  const int to = tid >> 6;   // wave id: 8 o's per wave
  const int tq = tid & 63;

  __shared__ float Xs[ICB][7][68];
  __shared__ float Ws[ICB * 9 * 32];
  __shared__ float sty[512];

  for (int i = tid; i < 512; i += 256) sty[i] = styles[n * 512 + i];

  const int r0out = spBase / 66;
  const int rIn0 = r0out - 2;
  int lofs[4]; int cloc[4]; bool valid[4];
#pragma unroll
  for (int ss = 0; ss < 4; ++ss) {
    int sp = spBase + tq + ss * 64;
    int r = sp / 66, c = sp % 66;
    lofs[ss] = (r - r0out) * 68 + c;   // LDS row/col base (kx,ky added later)
    cloc[ss] = c;
    valid[ss] = (sp < 4356);
  }

  float acc[8][4];
#pragma unroll
  for (int oo = 0; oo < 8; ++oo)
#pragma unroll
    for (int ss = 0; ss < 4; ++ss) acc[oo][ss] = 0.f;

  for (int ic0 = 0; ic0 < 512; ic0 += ICB) {
    __syncthreads();
    // stage X (zero-padded halo), scaled by styles
    for (int idx = tid; idx < ICB * 7 * 68; idx += 256) {
      int cc = idx % 68;
      int rest = idx / 68;
      int rr = rest % 7;
      int ii = rest / 7;
      int gr = rIn0 + rr, gc = cc - 2;
      float v = 0.f;
      if (gr >= 0 && gr < 64 && gc >= 0 && gc < 64)
        v = x[((n * 512 + ic0 + ii) * 64 + gr) * 64 + gc] * sty[ic0 + ii];
      Xs[ii][rr][cc] = v;
    }
    // stage W: [ii][k9][32 o]
    for (int idx = tid; idx < ICB * 9 * 32; idx += 256) {
      int ol = idx & 31;
      int rest = idx >> 5;        // ii*9 + k9
      Ws[idx] = wT[((ic0 * 9) + rest) * 512 + oBase + ol];
    }
    __syncthreads();

    const float* Xf = &Xs[0][0][0];
    for (int ii = 0; ii < ICB; ++ii) {
#pragma unroll
      for (int kx = 0; kx < 3; ++kx) {
#pragma unroll
        for (int ky = 0; ky < 3; ++ky) {
          float xv[4];
#pragma unroll
          for (int ss = 0; ss < 4; ++ss)
            xv[ss] = Xf[ii * 476 + lofs[ss] + kx * 68 + ky];
          const float* wp = &Ws[((ii * 3 + kx) * 3 + ky) * 32 + to * 8];
          float4 w0 = *(const float4*)(wp);
          float4 w1 = *(const float4*)(wp + 4);
          float wv[8] = {w0.x, w0.y, w0.z, w0.w, w1.x, w1.y, w1.z, w1.w};
#pragma unroll
          for (int oo = 0; oo < 8; ++oo)
#pragma unroll
            for (int ss = 0; ss < 4; ++ss)
              acc[oo][ss] = fmaf(wv[oo], xv[ss], acc[oo][ss]);
        }
      }
    }
  }

#pragma unroll
  for (int oo = 0; oo < 8; ++oo) {
    int o = oBase + to * 8 + oo;
    float cf = coef[n * 512 + o];
    float* outp = convout + (size_t)(n * 512 + o) * 4356;
#pragma unroll
    for (int ss = 0; ss < 4; ++ss) {
      int sp = spBase + tq + ss * 64;
      if (valid[ss]) outp[sp] = acc[oo][ss] * cf;
    }
  }
  (void)cloc;
}

// Fused bias + up-FIR(x2, gain 4) + lrelu*sqrt2 + clamp + down-FIR(/2).
// One block = one (n,c) image x 16 output rows. All in LDS.
__global__ __launch_bounds__(256) void k_flrelu(const float* __restrict__ convout,
    const float* __restrict__ cbias, const float* __restrict__ fu,
    const float* __restrict__ fd, float* __restrict__ out) {
  const int img = blockIdx.x >> 2;       // n*512+c
  const int tile = blockIdx.x & 3;
  const int p0 = tile * 16;              // output rows [p0, p0+16)
  const int c = img & 511;
  const int tid = threadIdx.x;
  const int wv = tid >> 6, ln = tid & 63;

  __shared__ float Bs[42 * 66];          // vertical-up rows r = 2p0+k, k in [0,42)
  __shared__ float AV[2688];             // A (<=26x66=1716) then aliased as V (42x64)
  __shared__ float Urow[4][160];         // per-wave U row
  __shared__ float fup[12], fdnr[12];

  if (tid < 12) { fup[tid] = fu[tid]; fdnr[tid] = fd[11 - tid]; }

  const int a0 = imax(0, p0 - 4);
  const int a1 = imin(65, p0 + 21);
  const int na = a1 - a0 + 1;

  // stage 1: A = convout rows [a0,a1] + bias
  {
    const float* src = convout + (size_t)img * 4356 + a0 * 66;
    const float bias = cbias[c];
    for (int t = tid; t < na * 66; t += 256) AV[t] = src[t] + bias;
  }
  __syncthreads();

  // stage 2: B[k][c2], r = 2p0+k: vertical up-FIR (6 taps)
  for (int t = tid; t < 42 * 66; t += 256) {
    int k = t / 66, c2 = t % 66;
    int r = 2 * p0 + k;
    int hlo = (r >= 9) ? ((r - 8) >> 1) : 0;   // ceil((r-9)/2)
    int hhi = imin(65, (r + 2) >> 1);
    float s = 0.f;
    for (int h = hlo; h <= hhi; ++h)
      s = fmaf(fup[r + 2 - 2 * h], AV[(h - a0) * 66 + c2], s);
    Bs[t] = s;
  }
  __syncthreads();

  // stage 3: per-wave rows: horizontal up-FIR + gain + lrelu + clamp -> U,
  // then horizontal down-FIR -> V[k][q] (V aliases A's LDS; A is dead)
  float* Vs = AV;
  for (int k = wv; k < 42; k += 4) {
    float* U = &Urow[wv][0];
    const float* Br = &Bs[k * 66];
    for (int cc = ln; cc < 138; cc += 64) {
      int wlo = (cc >= 9) ? ((cc - 8) >> 1) : 0;
      int whi = imin(65, (cc + 2) >> 1);
      float s = 0.f;
      for (int w2 = wlo; w2 <= whi; ++w2)
        s = fmaf(fup[cc + 2 - 2 * w2], Br[w2], s);
      s *= 4.f;                                   // upfirdn gain = up^2
      s = (s >= 0.f ? s : 0.2f * s) * SQRT2_F;    // lrelu * sqrt(2)
      s = fminf(256.f, fmaxf(-256.f, s));         // clamp
      U[cc] = s;
    }
    // wave-private LDS write->read; ordered by lgkmcnt within the wave
    int q = ln;
    float s = 0.f;
#pragma unroll
    for (int j = 0; j < 12; ++j) s = fmaf(fdnr[j], U[2 * q + j], s);
    Vs[k * 64 + q] = s;
  }
  __syncthreads();

  // stage 4: vertical down-FIR -> out rows [p0, p0+16)
  for (int t = tid; t < 1024; t += 256) {
    int pr = t >> 6, q = t & 63;
    int kb = 2 * pr;
    float s = 0.f;
#pragma unroll
    for (int j = 0; j < 12; ++j) s = fmaf(fdnr[j], Vs[(kb + j) * 64 + q], s);
    out[(size_t)img * 4096 + (p0 + pr) * 64 + q] = s;
  }
}

extern "C" void kernel_launch(void* const* d_in, const int* in_sizes, int n_in,
                              void* d_out, int out_size, void* d_ws, size_t ws_size,
                              hipStream_t stream) {
  const float* x   = (const float*)d_in[0];
  const float* w   = (const float*)d_in[1];
  const float* aw  = (const float*)d_in[2];
  const float* ab  = (const float*)d_in[3];
  const float* cw  = (const float*)d_in[4];
  const float* cb  = (const float*)d_in[5];
  const float* fu  = (const float*)d_in[6];
  const float* fd  = (const float*)d_in[7];
  const float* ema = (const float*)d_in[8];
  float* out = (float*)d_out;

  float* ws      = (float*)d_ws;
  float* convout = ws;                          // 8*512*66*66 = 17,842,176
  float* wT      = convout + 17842176;          // 2,359,296
  float* styles  = wT + 2359296;                // 4096
  float* wsq     = styles + 4096;               // 262,144
  float* wscale  = wsq + 262144;                // 512
  float* coef    = wscale + 512;                // 4096
  float* sg      = coef + 4096;                 // 1

  k_styles<<<16, 256, 0, stream>>>(w, aw, ab, styles);
  k_wstats<<<512, 256, 0, stream>>>(cw, wsq, wscale);
  k_sg<<<1, 256, 0, stream>>>(styles, sg);
  k_coef<<<16, 256, 0, stream>>>(styles, wsq, wscale, sg, ema, coef);
  k_wT<<<9216, 256, 0, stream>>>(cw, wT);
  k_conv<<<dim3(18, 16, 8), 256, 0, stream>>>(x, wT, styles, coef, convout);
  k_flrelu<<<16384, 256, 0, stream>>>(convout, cb, fu, fd, out);
}

// Round 2
// 568.240 us; speedup vs baseline: 5.6013x; 5.6013x over previous
//
#include <hip/hip_runtime.h>
#include <cstdint>

#define DEV __device__ __forceinline__

static constexpr float INV_SQRT_W = 0.04419417382415922f; // 1/sqrt(512)
static constexpr float SQRT2_F    = 1.41421356237309515f;

typedef _Float16 half8 __attribute__((ext_vector_type(8)));
typedef float    f32x4 __attribute__((ext_vector_type(4)));

#define GLL16(g, l) __builtin_amdgcn_global_load_lds( \
    (const __attribute__((address_space(1))) void*)(g), \
    (__attribute__((address_space(3))) void*)(l), 16, 0, 0)

DEV int imax(int a, int b) { return a > b ? a : b; }
DEV int imin(int a, int b) { return a < b ? a : b; }

// styles[n][c] = w[n]·aw[c] / sqrt(512) + ab[c]
__global__ __launch_bounds__(256) void k_styles(const float* __restrict__ w,
    const float* __restrict__ aw, const float* __restrict__ ab,
    float* __restrict__ styles) {
  int t = blockIdx.x * 256 + threadIdx.x;        // 4096
  int n = t >> 9, c = t & 511;
  const float* wr = w + n * 512;
  const float* ar = aw + c * 512;
  float s = 0.f;
  for (int k = 0; k < 512; ++k) s = fmaf(wr[k], ar[k], s);
  styles[t] = s * INV_SQRT_W + ab[c];
}

// wsq[o][i] = sum_k w[o,i,k]^2 ; wscale[o] = rsqrt(mean over 4608)
__global__ __launch_bounds__(256) void k_wstats(const float* __restrict__ cw,
    float* __restrict__ wsq, float* __restrict__ wscale) {
  int o = blockIdx.x;
  __shared__ float red[256];
  float tot = 0.f;
  for (int i = threadIdx.x; i < 512; i += 256) {
    const float* p = cw + (o * 512 + i) * 9;
    float s = 0.f;
#pragma unroll
    for (int k = 0; k < 9; ++k) s = fmaf(p[k], p[k], s);
    wsq[o * 512 + i] = s;
    tot += s;
  }
  red[threadIdx.x] = tot;
  __syncthreads();
  for (int st = 128; st > 0; st >>= 1) {
    if (threadIdx.x < st) red[threadIdx.x] += red[threadIdx.x + st];
    __syncthreads();
  }
  if (threadIdx.x == 0) wscale[o] = rsqrtf(red[0] / 4608.f);
}

// sg = rsqrt(mean(styles^2)) over all 4096
__global__ __launch_bounds__(256) void k_sg(const float* __restrict__ styles,
                                            float* __restrict__ sg) {
  __shared__ float red[256];
  float s = 0.f;
  for (int t = threadIdx.x; t < 4096; t += 256) { float v = styles[t]; s = fmaf(v, v, s); }
  red[threadIdx.x] = s;
  __syncthreads();
  for (int st = 128; st > 0; st >>= 1) {
    if (threadIdx.x < st) red[threadIdx.x] += red[threadIdx.x + st];
    __syncthreads();
  }
  if (threadIdx.x == 0) sg[0] = rsqrtf(red[0] / 4096.f);
}

// coef[n][o] = ig * rsqrt(a^2*Q + 1e-8), a = wscale[o]*sg
// (conv already computed with w*wscale and x*styles*sg folded in)
__global__ __launch_bounds__(256) void k_coef(const float* __restrict__ styles,
    const float* __restrict__ wsq, const float* __restrict__ wscale,
    const float* __restrict__ sg, const float* __restrict__ ema,
    float* __restrict__ coef) {
  int n = blockIdx.x >> 1;
  int o = ((blockIdx.x & 1) << 8) + threadIdx.x;
  __shared__ float s2[512];
  for (int i = threadIdx.x; i < 512; i += 256) { float v = styles[n * 512 + i]; s2[i] = v * v; }
  __syncthreads();
  const float* wq = wsq + o * 512;
  float Q = 0.f;
  for (int i = 0; i < 512; ++i) Q = fmaf(s2[i], wq[i], Q);
  float a = wscale[o] * sg[0];
  float ig = rsqrtf(ema[0]);
  coef[n * 512 + o] = ig * rsqrtf(a * a * Q + 1e-8f);
}

// xT[n][ic][r][c][slot s][j] = f16( x[n, ic*32 + (s^sig(r,c))*8+j, r, c] * styles * sg )
// sig(r,c) = ((r*68 + c + 2) >> 1) & 3  -- bank swizzle baked at 16B granularity
__global__ __launch_bounds__(256) void k_xprep(const float* __restrict__ x,
    const float* __restrict__ styles, const float* __restrict__ sg,
    _Float16* __restrict__ xT) {
  const int b = blockIdx.x;                 // 8*16*64 = 8192
  const int r = b & 63, ic = (b >> 6) & 15, n = b >> 10;
  const int tid = threadIdx.x;
  const int c = tid >> 2, s = tid & 3;
  const float sgv = sg[0];
  const int sig = ((r * 68 + c + 2) >> 1) & 3;
  const int i0 = ic * 32 + (s ^ sig) * 8;
  half8 v;
#pragma unroll
  for (int j = 0; j < 8; ++j) {
    int i = i0 + j;
    float xv = x[(((size_t)n * 512 + i) * 64 + r) * 64 + c];
    v[j] = (_Float16)(xv * styles[n * 512 + i] * sgv);
  }
  *(half8*)(xT + ((((size_t)(n * 16 + ic) * 64 + r) * 64 + c) * 32) + s * 8) = v;
}

// w2[k9][ic][o][iw] = f16( cw[o, ic*32+iw, k9] * wscale[o] )   (no swizzle: read to regs)
__global__ __launch_bounds__(256) void k_wprep(const float* __restrict__ cw,
    const float* __restrict__ wscale, _Float16* __restrict__ w2) {
  int t = blockIdx.x * 256 + threadIdx.x;    // 294912 slots of 8 halfs
  int s = t & 3;
  int o = (t >> 2) & 511;
  int ic = (t >> 11) & 15;
  int k9 = t >> 15;                          // 0..8
  float wsc = wscale[o];
  half8 v;
#pragma unroll
  for (int j = 0; j < 8; ++j) {
    int i = ic * 32 + s * 8 + j;
    v[j] = (_Float16)(cw[((size_t)o * 512 + i) * 9 + k9] * wsc);
  }
  *(half8*)(w2 + (size_t)t * 8) = v;
}

// Implicit-GEMM conv via MFMA f16. Block: 128 o x 128 flat-p, 4 waves (2x2) of 64x64.
// A (weights) streamed from global to regs; B (patch) from double-buffered LDS.
__global__ __launch_bounds__(256, 2) void k_conv(
    const _Float16* __restrict__ xT, const _Float16* __restrict__ w2,
    const float* __restrict__ coef, float* __restrict__ convout) {
  const int n = blockIdx.z;
  const int oBase = blockIdx.y * 128;
  const int p0 = blockIdx.x * 128;
  const int R0 = p0 / 66;
  const int tid = threadIdx.x;
  const int wave = tid >> 6;
  const int lane = tid & 63;
  const int wo = wave >> 1, wp = wave & 1;
  const int isub = lane >> 4;
  const int l15 = lane & 15;

  __shared__ _Float16 patch[2][10880];   // [5][68][32] halfs each, 21760 B per buf

  // per-nt output pixel coords (fixed per lane for the whole kernel)
  int rloc[4], rr2[4], cc[4];
#pragma unroll
  for (int nt = 0; nt < 4; ++nt) {
    int p = p0 + wp * 64 + nt * 16 + l15;
    if (p > 4355) p = 4355;
    int r = p / 66;
    rloc[nt] = r - R0;            // 0..2
    rr2[nt] = r - 2;              // rin base (dr=0)
    cc[nt] = p - r * 66;
  }

  f32x4 acc[4][4];
#pragma unroll
  for (int mt = 0; mt < 4; ++mt)
#pragma unroll
    for (int nt = 0; nt < 4; ++nt) acc[mt][nt] = (f32x4){0.f, 0.f, 0.f, 0.f};

  const int oA = oBase + wo * 64 + l15;
  const _Float16* wp0 = w2 + (size_t)oA * 32 + isub * 8;  // + ((k9*16+ic)*512 + mt*16)*32

  // ---- patch staging (global_load_lds, 16B/thread; pads zeroed via ds_write) ----
  auto stage_patch = [&](int ic, int buf) {
    const _Float16* src = xT + ((size_t)(n * 16 + ic) * 4096) * 32;
    _Float16* dst = &patch[buf][0];
#pragma unroll
    for (int rl = 0; rl < 5; ++rl) {
      int rin = R0 - 2 + rl;
      if (rin >= 0 && rin < 64)
        GLL16(src + (size_t)rin * 2048 + tid * 8, dst + (rl * 68 + 2) * 32 + tid * 8);
    }
    if (tid < 80) {                       // side pad cols: 5 rows x {0,1,66,67} x 4 slots
      int pix = tid >> 2, s = tid & 3;
      int rl = pix >> 2, ci = pix & 3;
      int cl = (ci < 2) ? ci : (ci + 64);
      half8 z = {};
      *(half8*)(dst + (rl * 68 + cl) * 32 + s * 8) = z;
    }
#pragma unroll
    for (int rl = 0; rl < 5; ++rl) {
      int rin = R0 - 2 + rl;
      if (rin < 0 || rin >= 64) {
        for (int u = tid; u < 272; u += 256) {   // 68 pixels x 4 slots
          half8 z = {};
          *(half8*)(dst + rl * 68 * 32 + u * 8) = z;
        }
      }
    }
  };

  stage_patch(0, 0);
  __syncthreads();

  for (int ic = 0; ic < 16; ++ic) {
    const int buf = ic & 1;
    if (ic < 15) stage_patch(ic + 1, buf ^ 1);
    const _Float16* pb = &patch[buf][0];

#pragma unroll
    for (int k9 = 0; k9 < 9; ++k9) {
      const int dr = k9 / 3, dc = k9 % 3;
      half8 aF[4];
#pragma unroll
      for (int mt = 0; mt < 4; ++mt)
        aF[mt] = *(const half8*)(wp0 + ((size_t)(k9 * 16 + ic) * 512 + mt * 16) * 32);
#pragma unroll
      for (int nt = 0; nt < 4; ++nt) {
        int rl = rloc[nt] + dr;
        int cl = cc[nt] + dc;
        int sig = (((rr2[nt] + dr) * 68 + cl) >> 1) & 3;
        int ah = (rl * 68 + cl) * 32 + ((isub ^ sig) << 3);
        half8 bF = *(const half8*)(pb + ah);
#pragma unroll
        for (int mt = 0; mt < 4; ++mt)
          acc[mt][nt] = __builtin_amdgcn_mfma_f32_16x16x32_f16(aF[mt], bF, acc[mt][nt], 0, 0, 0);
      }
    }
    __syncthreads();
  }

  // epilogue: C layout col=lane&15 (p), row=isub*4+j (o); scale by coef
#pragma unroll
  for (int mt = 0; mt < 4; ++mt) {
    const int o = oBase + wo * 64 + mt * 16 + isub * 4;
#pragma unroll
    for (int j = 0; j < 4; ++j) {
      const float cf = coef[n * 512 + o + j];
      float* outp = convout + ((size_t)(n * 512) + o + j) * 4356;
#pragma unroll
      for (int nt = 0; nt < 4; ++nt) {
        int p = p0 + wp * 64 + nt * 16 + l15;
        if (p < 4356) outp[p] = acc[mt][nt][j] * cf;
      }
    }
  }
}

// Fused bias + up-FIR(x2, gain 4) + lrelu*sqrt2 + clamp + down-FIR(/2).
__global__ __launch_bounds__(256) void k_flrelu(const float* __restrict__ convout,
    const float* __restrict__ cbias, const float* __restrict__ fu,
    const float* __restrict__ fd, float* __restrict__ out) {
  const int img = blockIdx.x >> 2;       // n*512+c
  const int tile = blockIdx.x & 3;
  const int p0 = tile * 16;              // output rows [p0, p0+16)
  const int c = img & 511;
  const int tid = threadIdx.x;
  const int wv = tid >> 6, ln = tid & 63;

  __shared__ float Bs[42 * 66];
  __shared__ float AV[2688];
  __shared__ float Urow[4][160];
  __shared__ float fup[12], fdnr[12];

  if (tid < 12) { fup[tid] = fu[tid]; fdnr[tid] = fd[11 - tid]; }

  const int a0 = imax(0, p0 - 4);
  const int a1 = imin(65, p0 + 21);
  const int na = a1 - a0 + 1;

  {
    const float* src = convout + (size_t)img * 4356 + a0 * 66;
    const float bias = cbias[c];
    for (int t = tid; t < na * 66; t += 256) AV[t] = src[t] + bias;
  }
  __syncthreads();

  for (int t = tid; t < 42 * 66; t += 256) {
    int k = t / 66, c2 = t % 66;
    int r = 2 * p0 + k;
    int hlo = (r >= 9) ? ((r - 8) >> 1) : 0;
    int hhi = imin(65, (r + 2) >> 1);
    float s = 0.f;
    for (int h = hlo; h <= hhi; ++h)
      s = fmaf(fup[r + 2 - 2 * h], AV[(h - a0) * 66 + c2], s);
    Bs[t] = s;
  }
  __syncthreads();

  float* Vs = AV;
  for (int k = wv; k < 42; k += 4) {
    float* U = &Urow[wv][0];
    const float* Br = &Bs[k * 66];
    for (int cc2 = ln; cc2 < 138; cc2 += 64) {
      int wlo = (cc2 >= 9) ? ((cc2 - 8) >> 1) : 0;
      int whi = imin(65, (cc2 + 2) >> 1);
      float s = 0.f;
      for (int w2 = wlo; w2 <= whi; ++w2)
        s = fmaf(fup[cc2 + 2 - 2 * w2], Br[w2], s);
      s *= 4.f;
      s = (s >= 0.f ? s : 0.2f * s) * SQRT2_F;
      s = fminf(256.f, fmaxf(-256.f, s));
      U[cc2] = s;
    }
    int q = ln;
    float s = 0.f;
#pragma unroll
    for (int j = 0; j < 12; ++j) s = fmaf(fdnr[j], U[2 * q + j], s);
    Vs[k * 64 + q] = s;
  }
  __syncthreads();

  for (int t = tid; t < 1024; t += 256) {
    int pr = t >> 6, q = t & 63;
    int kb = 2 * pr;
    float s = 0.f;
#pragma unroll
    for (int j = 0; j < 12; ++j) s = fmaf(fdnr[j], Vs[(kb + j) * 64 + q], s);
    out[(size_t)img * 4096 + (p0 + pr) * 64 + q] = s;
  }
}

extern "C" void kernel_launch(void* const* d_in, const int* in_sizes, int n_in,
                              void* d_out, int out_size, void* d_ws, size_t ws_size,
                              hipStream_t stream) {
  const float* x   = (const float*)d_in[0];
  const float* w   = (const float*)d_in[1];
  const float* aw  = (const float*)d_in[2];
  const float* ab  = (const float*)d_in[3];
  const float* cw  = (const float*)d_in[4];
  const float* cb  = (const float*)d_in[5];
  const float* fu  = (const float*)d_in[6];
  const float* fd  = (const float*)d_in[7];
  const float* ema = (const float*)d_in[8];
  float* out = (float*)d_out;

  float* ws      = (float*)d_ws;
  float* convout = ws;                          // 17,842,176 f32
  float* styles  = convout + 17842176;          // 4096
  float* wsq     = styles + 4096;               // 262,144
  float* wscale  = wsq + 262144;                // 512
  float* coef    = wscale + 512;                // 4096
  float* sg      = coef + 4096;                 // 8 (pad)
  _Float16* xT   = (_Float16*)(sg + 8);         // 16,777,216 halfs
  _Float16* w2   = (_Float16*)((float*)(sg + 8) + 8388608); // 2,359,296 halfs

  k_styles<<<16, 256, 0, stream>>>(w, aw, ab, styles);
  k_sg<<<1, 256, 0, stream>>>(styles, sg);
  k_wstats<<<512, 256, 0, stream>>>(cw, wsq, wscale);
  k_coef<<<16, 256, 0, stream>>>(styles, wsq, wscale, sg, ema, coef);
  k_xprep<<<8192, 256, 0, stream>>>(x, styles, sg, xT);
  k_wprep<<<1152, 256, 0, stream>>>(cw, wscale, w2);
  k_conv<<<dim3(35, 4, 8), 256, 0, stream>>>(xT, w2, coef, convout);
  k_flrelu<<<16384, 256, 0, stream>>>(convout, cb, fu, fd, out);
}

// Round 4
// 488.116 us; speedup vs baseline: 6.5207x; 1.1641x over previous
//
#include <hip/hip_runtime.h>
#include <cstdint>

#define DEV __device__ __forceinline__

static constexpr float INV_SQRT_W = 0.04419417382415922f; // 1/sqrt(512)
static constexpr float SQRT2_F    = 1.41421356237309515f;

typedef _Float16 half8 __attribute__((ext_vector_type(8)));
typedef float    f32x4 __attribute__((ext_vector_type(4)));

#define GLL16(g, l) __builtin_amdgcn_global_load_lds( \
    (const __attribute__((address_space(1))) void*)(g), \
    (__attribute__((address_space(3))) void*)(l), 16, 0, 0)

DEV int imax(int a, int b) { return a > b ? a : b; }
DEV int imin(int a, int b) { return a < b ? a : b; }

// styles[n][c] = w[n]·aw[c] / sqrt(512) + ab[c]
__global__ __launch_bounds__(256) void k_styles(const float* __restrict__ w,
    const float* __restrict__ aw, const float* __restrict__ ab,
    float* __restrict__ styles) {
  int t = blockIdx.x * 256 + threadIdx.x;        // 4096
  int n = t >> 9, c = t & 511;
  const float* wr = w + n * 512;
  const float* ar = aw + c * 512;
  float s = 0.f;
  for (int k = 0; k < 512; ++k) s = fmaf(wr[k], ar[k], s);
  styles[t] = s * INV_SQRT_W + ab[c];
}

// wsq[o][i] = sum_k w[o,i,k]^2 ; wscale[o] = rsqrt(mean over 4608)
__global__ __launch_bounds__(256) void k_wstats(const float* __restrict__ cw,
    float* __restrict__ wsq, float* __restrict__ wscale) {
  int o = blockIdx.x;
  __shared__ float red[256];
  float tot = 0.f;
  for (int i = threadIdx.x; i < 512; i += 256) {
    const float* p = cw + (o * 512 + i) * 9;
    float s = 0.f;
#pragma unroll
    for (int k = 0; k < 9; ++k) s = fmaf(p[k], p[k], s);
    wsq[o * 512 + i] = s;
    tot += s;
  }
  red[threadIdx.x] = tot;
  __syncthreads();
  for (int st = 128; st > 0; st >>= 1) {
    if (threadIdx.x < st) red[threadIdx.x] += red[threadIdx.x + st];
    __syncthreads();
  }
  if (threadIdx.x == 0) wscale[o] = rsqrtf(red[0] / 4608.f);
}

// sg = rsqrt(mean(styles^2)) over all 4096
__global__ __launch_bounds__(256) void k_sg(const float* __restrict__ styles,
                                            float* __restrict__ sg) {
  __shared__ float red[256];
  float s = 0.f;
  for (int t = threadIdx.x; t < 4096; t += 256) { float v = styles[t]; s = fmaf(v, v, s); }
  red[threadIdx.x] = s;
  __syncthreads();
  for (int st = 128; st > 0; st >>= 1) {
    if (threadIdx.x < st) red[threadIdx.x] += red[threadIdx.x + st];
    __syncthreads();
  }
  if (threadIdx.x == 0) sg[0] = rsqrtf(red[0] / 4096.f);
}

// coef[n][o] = ig * rsqrt(a^2*Q + 1e-8), a = wscale[o]*sg
__global__ __launch_bounds__(256) void k_coef(const float* __restrict__ styles,
    const float* __restrict__ wsq, const float* __restrict__ wscale,
    const float* __restrict__ sg, const float* __restrict__ ema,
    float* __restrict__ coef) {
  int n = blockIdx.x >> 1;
  int o = ((blockIdx.x & 1) << 8) + threadIdx.x;
  __shared__ float s2[512];
  for (int i = threadIdx.x; i < 512; i += 256) { float v = styles[n * 512 + i]; s2[i] = v * v; }
  __syncthreads();
  const float* wq = wsq + o * 512;
  float Q = 0.f;
  for (int i = 0; i < 512; ++i) Q = fmaf(s2[i], wq[i], Q);
  float a = wscale[o] * sg[0];
  float ig = rsqrtf(ema[0]);
  coef[n * 512 + o] = ig * rsqrtf(a * a * Q + 1e-8f);
}

// xT[n][ic][r][c][slot s][j] = f16( x[n, ic*32 + (s^sig(r,c))*8+j, r, c] * styles * sg )
__global__ __launch_bounds__(256) void k_xprep(const float* __restrict__ x,
    const float* __restrict__ styles, const float* __restrict__ sg,
    _Float16* __restrict__ xT) {
  const int b = blockIdx.x;                 // 8*16*64 = 8192
  const int r = b & 63, ic = (b >> 6) & 15, n = b >> 10;
  const int tid = threadIdx.x;
  const int c = tid >> 2, s = tid & 3;
  const float sgv = sg[0];
  const int sig = ((r * 68 + c + 2) >> 1) & 3;
  const int i0 = ic * 32 + (s ^ sig) * 8;
  half8 v;
#pragma unroll
  for (int j = 0; j < 8; ++j) {
    int i = i0 + j;
    float xv = x[(((size_t)n * 512 + i) * 64 + r) * 64 + c];
    v[j] = (_Float16)(xv * styles[n * 512 + i] * sgv);
  }
  *(half8*)(xT + ((((size_t)(n * 16 + ic) * 64 + r) * 64 + c) * 32) + s * 8) = v;
}

// w2[k9][ic][o][iw] = f16( cw[o, ic*32+iw, k9] * wscale[o] )
__global__ __launch_bounds__(256) void k_wprep(const float* __restrict__ cw,
    const float* __restrict__ wscale, _Float16* __restrict__ w2) {
  int t = blockIdx.x * 256 + threadIdx.x;    // 294912 slots of 8 halfs
  int s = t & 3;
  int o = (t >> 2) & 511;
  int ic = (t >> 11) & 15;
  int k9 = t >> 15;                          // 0..8
  float wsc = wscale[o];
  half8 v;
#pragma unroll
  for (int j = 0; j < 8; ++j) {
    int i = ic * 32 + s * 8 + j;
    v[j] = (_Float16)(cw[((size_t)o * 512 + i) * 9 + k9] * wsc);
  }
  *(half8*)(w2 + (size_t)t * 8) = v;
}

// Implicit-GEMM conv via MFMA f16. (unchanged from R2 — verified correct)
__global__ __launch_bounds__(256, 2) void k_conv(
    const _Float16* __restrict__ xT, const _Float16* __restrict__ w2,
    const float* __restrict__ coef, float* __restrict__ convout) {
  const int n = blockIdx.z;
  const int oBase = blockIdx.y * 128;
  const int p0 = blockIdx.x * 128;
  const int R0 = p0 / 66;
  const int tid = threadIdx.x;
  const int wave = tid >> 6;
  const int lane = tid & 63;
  const int wo = wave >> 1, wp = wave & 1;
  const int isub = lane >> 4;
  const int l15 = lane & 15;

  __shared__ _Float16 patch[2][10880];   // [5][68][32] halfs each

  int rloc[4], rr2[4], cc[4];
#pragma unroll
  for (int nt = 0; nt < 4; ++nt) {
    int p = p0 + wp * 64 + nt * 16 + l15;
    if (p > 4355) p = 4355;
    int r = p / 66;
    rloc[nt] = r - R0;
    rr2[nt] = r - 2;
    cc[nt] = p - r * 66;
  }

  f32x4 acc[4][4];
#pragma unroll
  for (int mt = 0; mt < 4; ++mt)
#pragma unroll
    for (int nt = 0; nt < 4; ++nt) acc[mt][nt] = (f32x4){0.f, 0.f, 0.f, 0.f};

  const int oA = oBase + wo * 64 + l15;
  const _Float16* wp0 = w2 + (size_t)oA * 32 + isub * 8;

  auto stage_patch = [&](int ic, int buf) {
    const _Float16* src = xT + ((size_t)(n * 16 + ic) * 4096) * 32;
    _Float16* dst = &patch[buf][0];
#pragma unroll
    for (int rl = 0; rl < 5; ++rl) {
      int rin = R0 - 2 + rl;
      if (rin >= 0 && rin < 64)
        GLL16(src + (size_t)rin * 2048 + tid * 8, dst + (rl * 68 + 2) * 32 + tid * 8);
    }
    if (tid < 80) {
      int pix = tid >> 2, s = tid & 3;
      int rl = pix >> 2, ci = pix & 3;
      int cl = (ci < 2) ? ci : (ci + 64);
      half8 z = {};
      *(half8*)(dst + (rl * 68 + cl) * 32 + s * 8) = z;
    }
#pragma unroll
    for (int rl = 0; rl < 5; ++rl) {
      int rin = R0 - 2 + rl;
      if (rin < 0 || rin >= 64) {
        for (int u = tid; u < 272; u += 256) {
          half8 z = {};
          *(half8*)(dst + rl * 68 * 32 + u * 8) = z;
        }
      }
    }
  };

  stage_patch(0, 0);
  __syncthreads();

  for (int ic = 0; ic < 16; ++ic) {
    const int buf = ic & 1;
    if (ic < 15) stage_patch(ic + 1, buf ^ 1);
    const _Float16* pb = &patch[buf][0];

#pragma unroll
    for (int k9 = 0; k9 < 9; ++k9) {
      const int dr = k9 / 3, dc = k9 % 3;
      half8 aF[4];
#pragma unroll
      for (int mt = 0; mt < 4; ++mt)
        aF[mt] = *(const half8*)(wp0 + ((size_t)(k9 * 16 + ic) * 512 + mt * 16) * 32);
#pragma unroll
      for (int nt = 0; nt < 4; ++nt) {
        int rl = rloc[nt] + dr;
        int cl = cc[nt] + dc;
        int sig = (((rr2[nt] + dr) * 68 + cl) >> 1) & 3;
        int ah = (rl * 68 + cl) * 32 + ((isub ^ sig) << 3);
        half8 bF = *(const half8*)(pb + ah);
#pragma unroll
        for (int mt = 0; mt < 4; ++mt)
          acc[mt][nt] = __builtin_amdgcn_mfma_f32_16x16x32_f16(aF[mt], bF, acc[mt][nt], 0, 0, 0);
      }
    }
    __syncthreads();
  }

#pragma unroll
  for (int mt = 0; mt < 4; ++mt) {
    const int o = oBase + wo * 64 + mt * 16 + isub * 4;
#pragma unroll
    for (int j = 0; j < 4; ++j) {
      const float cf = coef[n * 512 + o + j];
      float* outp = convout + ((size_t)(n * 512) + o + j) * 4356;
#pragma unroll
      for (int nt = 0; nt < 4; ++nt) {
        int p = p0 + wp * 64 + nt * 16 + l15;
        if (p < 4356) outp[p] = acc[mt][nt][j] * cf;
      }
    }
  }
}

// Fused bias + up-FIR(x2, polyphase) + lrelu + clamp + down-FIR(/2).
// NO cross-lane LDS sharing: every inter-thread value crosses a __syncthreads.
// Stage 3 recomputes the 12 upsampled values it needs per output col, per-lane.
__global__ __launch_bounds__(256) void k_flrelu(const float* __restrict__ convout,
    const float* __restrict__ cbias, const float* __restrict__ fu,
    const float* __restrict__ fd, float* __restrict__ out) {
  const int img = blockIdx.x >> 2;       // n*512+c
  const int tile = blockIdx.x & 3;
  const int p0 = tile * 16;              // output rows [p0, p0+16)
  const int c = img & 511;
  const int tid = threadIdx.x;
  const int wv = tid >> 6, ln = tid & 63;

  __shared__ float As[26 * 68];          // conv rows p0-4 .. p0+21 (+bias), 0 outside
  __shared__ float Bs[42 * 76];          // v-up rows, col offset +4, zero aprons
  __shared__ float Vs[42 * 64];          // after horizontal up+lrelu+down

  // filters in uniform registers (scalar loads; all indices static after unroll)
  float fupr[12], fdr[12];
#pragma unroll
  for (int j = 0; j < 12; ++j) { fupr[j] = fu[j]; fdr[j] = fd[11 - j]; }

  // stage 1: A rows [p0-4, p0+21] + bias; zero outside image
  {
    const float* src = convout + (size_t)img * 4356;
    const float bias = cbias[c];
    for (int t = tid; t < 26 * 68; t += 256) {
      int r = t / 68, cc2 = t - r * 68;
      int gr = p0 - 4 + r;
      float v = 0.f;
      if (cc2 < 66 && gr >= 0 && gr < 66) v = src[gr * 66 + cc2] + bias;
      As[t] = v;
    }
  }
  __syncthreads();

  // stage 2: vertical up-FIR, polyphase 6 taps. B[k][m], k in [0,42), m in [0,66).
  // r = 2p0+k, e = k&1, kk = (k-e)/2; A row idx = kk+5-j, tap fup[e+2j].
  for (int t = tid; t < 42 * 33; t += 256) {
    int k = t / 33, m2 = t - k * 33;
    int e = k & 1, kk = (k - e) >> 1;
    const float* Ab = &As[kk * 68 + 2 * m2];
    float sx = 0.f, sy = 0.f;
#pragma unroll
    for (int j = 0; j < 6; ++j) {
      float2 a = *(const float2*)(Ab + (5 - j) * 68);
      float f = e ? fupr[2 * j + 1] : fupr[2 * j];
      sx = fmaf(f, a.x, sx);
      sy = fmaf(f, a.y, sy);
    }
    float2 s2v = make_float2(sx, sy);
    *(float2*)&Bs[k * 76 + 4 + 2 * m2] = s2v;
  }
  // zero B aprons: cols [0,4) and [70,76) per row
  for (int t = tid; t < 42 * 10; t += 256) {
    int k = t / 10, ci = t - k * 10;
    int col = (ci < 4) ? ci : (66 + ci);
    Bs[k * 76 + col] = 0.f;
  }
  __syncthreads();

  // stage 3: lane ln computes V[k][ln] = sum_{jj<12} fd_r[jj] * LR(U[2ln+jj])
  // U[2(ln+d)+e] = sum_j fup[e+2j] * B[ln+d+1-j];  B[w] at Bs col w+4 (zero aprons).
  // b[t] = B[ln-4+t] = Bs[k*76 + ln + t], t in [0,11).
  for (int k = wv; k < 42; k += 4) {
    const float* Br = &Bs[k * 76 + ln];
    float b[11];
#pragma unroll
    for (int t = 0; t < 11; ++t) b[t] = Br[t];
    float v = 0.f;
#pragma unroll
    for (int d = 0; d < 6; ++d) {
      float ue = 0.f, uo = 0.f;
#pragma unroll
      for (int j = 0; j < 6; ++j) {
        float bb = b[d + 5 - j];
        ue = fmaf(fupr[2 * j], bb, ue);
        uo = fmaf(fupr[2 * j + 1], bb, uo);
      }
      // y = clamp(lrelu(4*u)*sqrt2, +-256) = clamp(u * (u>=0 ? 4sqrt2 : 0.8sqrt2), +-256)
      ue *= (ue >= 0.f) ? 5.65685424949238f : 1.13137084989848f;
      uo *= (uo >= 0.f) ? 5.65685424949238f : 1.13137084989848f;
      ue = fminf(256.f, fmaxf(-256.f, ue));
      uo = fminf(256.f, fmaxf(-256.f, uo));
      v = fmaf(fdr[2 * d], ue, v);
      v = fmaf(fdr[2 * d + 1], uo, v);
    }
    Vs[k * 64 + ln] = v;
  }
  __syncthreads();

  // stage 4: vertical down-FIR -> out rows [p0, p0+16)
  for (int t = tid; t < 1024; t += 256) {
    int pr = t >> 6, q = t & 63;
    const float* Vb = &Vs[2 * pr * 64 + q];
    float s = 0.f;
#pragma unroll
    for (int j = 0; j < 12; ++j) s = fmaf(fdr[j], Vb[j * 64], s);
    out[(size_t)img * 4096 + (p0 + pr) * 64 + q] = s;
  }
}

extern "C" void kernel_launch(void* const* d_in, const int* in_sizes, int n_in,
                              void* d_out, int out_size, void* d_ws, size_t ws_size,
                              hipStream_t stream) {
  const float* x   = (const float*)d_in[0];
  const float* w   = (const float*)d_in[1];
  const float* aw  = (const float*)d_in[2];
  const float* ab  = (const float*)d_in[3];
  const float* cw  = (const float*)d_in[4];
  const float* cb  = (const float*)d_in[5];
  const float* fu  = (const float*)d_in[6];
  const float* fd  = (const float*)d_in[7];
  const float* ema = (const float*)d_in[8];
  float* out = (float*)d_out;

  float* ws      = (float*)d_ws;
  float* convout = ws;                          // 17,842,176 f32
  float* styles  = convout + 17842176;          // 4096
  float* wsq     = styles + 4096;               // 262,144
  float* wscale  = wsq + 262144;                // 512
  float* coef    = wscale + 512;                // 4096
  float* sg      = coef + 4096;                 // 8 (pad)
  _Float16* xT   = (_Float16*)(sg + 8);         // 16,777,216 halfs
  _Float16* w2   = (_Float16*)((float*)(sg + 8) + 8388608); // 2,359,296 halfs

  k_styles<<<16, 256, 0, stream>>>(w, aw, ab, styles);
  k_sg<<<1, 256, 0, stream>>>(styles, sg);
  k_wstats<<<512, 256, 0, stream>>>(cw, wsq, wscale);
  k_coef<<<16, 256, 0, stream>>>(styles, wsq, wscale, sg, ema, coef);
  k_xprep<<<8192, 256, 0, stream>>>(x, styles, sg, xT);
  k_wprep<<<1152, 256, 0, stream>>>(cw, wscale, w2);
  k_conv<<<dim3(35, 4, 8), 256, 0, stream>>>(xT, w2, coef, convout);
  k_flrelu<<<16384, 256, 0, stream>>>(convout, cb, fu, fd, out);
}